// Round 13
// baseline (257.396 us; speedup 1.0000x reference)
//
#include <hip/hip_runtime.h>

// ---------------------------------------------------------------------------
// AlignableCaslAgent forward.  Inputs f32, outputs f32.
// Round 23 (resubmit; round-12 bench was a GPU-broker timeout, no signal):
// gates GEMM split-K 4 -> 10 (Kc=64): 128 -> 320 blocks (0.5 -> 1.25
// blocks/CU; half the GPU was provably idle).  Single-variable change on the
// verified 2-phase gemm (round 17's z=10 regression was confounded with the
// 8-wave repartition).  lstm_fin sums 10 slices (gatesp 20MB, L3-hot).
// Everything else identical to round 22 (248.1us best).
// ---------------------------------------------------------------------------

typedef unsigned short u16;
typedef unsigned int u32;
typedef __attribute__((ext_vector_type(8))) short bf16x8;
typedef __attribute__((ext_vector_type(4))) short bf16x4;
typedef __attribute__((ext_vector_type(4))) float f32x4;

__device__ __forceinline__ float b2f(u16 u) {
    union { u32 i; float f; } v; v.i = ((u32)u) << 16; return v.f;
}
__device__ __forceinline__ u16 f2b(float f) {
    union { float f; u32 i; } v; v.f = f;
    u32 r = v.i + 0x7fffu + ((v.i >> 16) & 1u);
    return (u16)(r >> 16);
}

// async global->LDS, 16B per lane; LDS dest = wave-uniform base + lane*16.
__device__ __forceinline__ void gl_lds16(const u16* g, u16* l) {
    __builtin_amdgcn_global_load_lds(
        (const __attribute__((address_space(1))) void*)g,
        (__attribute__((address_space(3))) void*)l,
        16, 0, 0);
}

// c1 LDS tile swizzle: XOR bits[6:4] with bits[9:7] (involution, keeps 16B
// alignment).  Valid per image region when region base % 1024 == 0.
__device__ __forceinline__ int swz(int byte) {
    return byte ^ (((byte >> 7) & 7) << 4);
}

// ---------------------------------------------------------------------------
// Fused conv tower, 2 images per block (round-20 version, arc closed).
// grid = (512, 2), 256 threads.  LDS 79424B -> 2 blocks/CU.
// ---------------------------------------------------------------------------
__global__ __launch_bounds__(256, 2) void tower_fused(
    const float* __restrict__ x,
    const u16* __restrict__ Wp1, const u16* __restrict__ Wp2,
    const u16* __restrict__ Wp3,
    const float* __restrict__ vb1, const float* __restrict__ ab1,
    const float* __restrict__ vb2, const float* __restrict__ ab2,
    const float* __restrict__ vb3, const float* __restrict__ ab3,
    u16* __restrict__ c3f)
{
    __shared__ __attribute__((aligned(16))) u16 scratch2[2 * 7056]; // img/c2L
    __shared__ __attribute__((aligned(16))) u16 c1L[2 * 400 * 32];  // swizzled

    const int tid = threadIdx.x;
    const int wave = tid >> 6, lane = tid & 63, quad = lane >> 4, l16 = lane & 15;
    const int bl0 = blockIdx.x * 2, t = blockIdx.y;
    const int wi = wave >> 1, lw = wave & 1;     // image index, local wave

    const u16* Wpt1 = Wp1 + t * 2048;
    const u16* Wpt2 = Wp2 + t * 32768;
    const u16* Wpt3 = Wp3 + t * 36864;

    // ---- conv1 weights first (in flight during image staging) ----
    bf16x8 bw[2][2];
#pragma unroll
    for (int ks = 0; ks < 2; ++ks)
#pragma unroll
        for (int ni = 0; ni < 2; ++ni)
            bw[ks][ni] = *(const bf16x8*)(Wpt1 + ((ks * 2 + ni) * 64 + lane) * 8);

    // ---- stage both images -> bf16 LDS ----
#pragma unroll
    for (int si = 0; si < 2; ++si) {
        const float* xim = x + ((long)(bl0 + si) * 2 + t) * 7056;
        u16* simg = scratch2 + si * 7056;
#pragma unroll
        for (int it = 0; it < 7; ++it) {
            const int e4 = (tid + it * 256) * 4;
            if (e4 < 7056) {
                float4 v = *(const float4*)(xim + e4);
                bf16x4 s;
                s[0] = (short)f2b(v.x); s[1] = (short)f2b(v.y);
                s[2] = (short)f2b(v.z); s[3] = (short)f2b(v.w);
                *(bf16x4*)(simg + e4) = s;
            }
        }
    }
    __syncthreads();

    const u16* simg = scratch2 + wi * 7056;      // this wave's image
    const int imgb = wi * 25600;                 // c1L image base (bytes)

    // ---- conv1: 400 outputs per image, K=64, OC=32; 12-13 tiles/wave ----
    {
        const float* b1 = t ? ab1 : vb1;
        const float bv0 = b1[l16], bv1 = b1[16 + l16];

        for (int tile = lw; tile < 25; tile += 2) {
            const int m = tile * 16 + l16;           // 0..399, always valid
            const int oy = m / 20, ox = m % 20;
            const u16* base = simg + (oy * 4) * 84 + ox * 4;
            const u16* ap0 = base + (quad) * 84;
            const u16* ap1 = base + (4 + quad) * 84;
            bf16x4 lo0 = *(const bf16x4*)(ap0);
            bf16x4 hi0 = *(const bf16x4*)(ap0 + 4);
            bf16x4 lo1 = *(const bf16x4*)(ap1);
            bf16x4 hi1 = *(const bf16x4*)(ap1 + 4);
            bf16x8 a0, a1;
#pragma unroll
            for (int j = 0; j < 4; ++j) {
                a0[j] = lo0[j]; a0[4 + j] = hi0[j];
                a1[j] = lo1[j]; a1[4 + j] = hi1[j];
            }
            f32x4 acc0 = (f32x4){0.f, 0.f, 0.f, 0.f};
            f32x4 acc1 = (f32x4){0.f, 0.f, 0.f, 0.f};
            acc0 = __builtin_amdgcn_mfma_f32_16x16x32_bf16(a0, bw[0][0], acc0, 0, 0, 0);
            acc1 = __builtin_amdgcn_mfma_f32_16x16x32_bf16(a0, bw[0][1], acc1, 0, 0, 0);
            acc0 = __builtin_amdgcn_mfma_f32_16x16x32_bf16(a1, bw[1][0], acc0, 0, 0, 0);
            acc1 = __builtin_amdgcn_mfma_f32_16x16x32_bf16(a1, bw[1][1], acc1, 0, 0, 0);
#pragma unroll
            for (int rr = 0; rr < 4; ++rr) {
                const int row = tile * 16 + quad * 4 + rr;
                *(u16*)((char*)c1L + imgb + swz((row * 32 + l16) * 2)) =
                    f2b(fmaxf(acc0[rr] + bv0, 0.f));
                *(u16*)((char*)c1L + imgb + swz((row * 32 + 16 + l16) * 2)) =
                    f2b(fmaxf(acc1[rr] + bv1, 0.f));
            }
        }
    }

    // ---- conv2 first weight set: issue BEFORE the barrier ----
    bf16x8 wb[2][4];
#pragma unroll
    for (int ni = 0; ni < 4; ++ni)
        wb[0][ni] = *(const bf16x8*)(Wpt2 + ((0 * 4 + ni) * 64 + lane) * 8);

    __syncthreads();

    // ---- conv2: 81 outputs per image, K=512, OC=64; 3 tiles/wave ----
    {
        const float* b2 = t ? ab2 : vb2;
        float bv[4];
#pragma unroll
        for (int ni = 0; ni < 4; ++ni) bv[ni] = b2[ni * 16 + l16];

        int bA[3];
#pragma unroll
        for (int j = 0; j < 3; ++j) {
            int m = (lw * 3 + j) * 16 + l16; if (m > 80) m = 80;
            const int oy = m / 9, ox = m % 9;
            bA[j] = ((oy * 2) * 20 + ox * 2) * 64 + quad * 16;   // bytes
        }

        f32x4 acc[3][4];
#pragma unroll
        for (int j = 0; j < 3; ++j)
#pragma unroll
            for (int ni = 0; ni < 4; ++ni)
                acc[j][ni] = (f32x4){0.f, 0.f, 0.f, 0.f};

        bf16x8 aA[3][2];
#pragma unroll
        for (int j = 0; j < 3; ++j)
            aA[j][0] = *(const bf16x8*)((const char*)c1L + imgb + swz(bA[j]));

#pragma unroll
        for (int pp = 0; pp < 16; ++pp) {    // window pixel = (ky,kx)
            const int cur = pp & 1, nxt = cur ^ 1;
            if (pp + 1 < 16) {
                const int pn = pp + 1;
                const int poffn = ((pn >> 2) * 20 + (pn & 3)) * 64;
#pragma unroll
                for (int ni = 0; ni < 4; ++ni)
                    wb[nxt][ni] = *(const bf16x8*)(Wpt2 + ((pn * 4 + ni) * 64 + lane) * 8);
#pragma unroll
                for (int j = 0; j < 3; ++j)
                    aA[j][nxt] = *(const bf16x8*)((const char*)c1L + imgb + swz(bA[j] + poffn));
            }
#pragma unroll
            for (int j = 0; j < 3; ++j)
#pragma unroll
                for (int ni = 0; ni < 4; ++ni)
                    acc[j][ni] = __builtin_amdgcn_mfma_f32_16x16x32_bf16(
                        aA[j][cur], wb[cur][ni], acc[j][ni], 0, 0, 0);
        }

        u16* c2L = scratch2 + wi * 5832;     // img data dead, alias [81][72]
#pragma unroll
        for (int j = 0; j < 3; ++j)
#pragma unroll
            for (int ni = 0; ni < 4; ++ni)
#pragma unroll
                for (int rr = 0; rr < 4; ++rr) {
                    const int r = (lw * 3 + j) * 16 + quad * 4 + rr;
                    if (r < 81)
                        c2L[r * 72 + ni * 16 + l16] =
                            f2b(fmaxf(acc[j][ni][rr] + bv[ni], 0.f));
                }
    }

    // ---- conv3 first weight set: issue BEFORE the barrier ----
    bf16x8 w3[2][4];
#pragma unroll
    for (int ni = 0; ni < 4; ++ni)
        w3[0][ni] = *(const bf16x8*)(Wpt3 + ((0 * 4 + ni) * 64 + lane) * 8);

    __syncthreads();

    // ---- conv3: 49 outputs per image, K=576, OC=64; 2 tiles/wave ----
    {
        const float* b3 = t ? ab3 : vb3;
        float bv[4];
#pragma unroll
        for (int ni = 0; ni < 4; ++ni) bv[ni] = b3[ni * 16 + l16];

        const u16* c2L = scratch2 + wi * 5832;
        const u16* base3[2];
#pragma unroll
        for (int j = 0; j < 2; ++j) {
            int m = (lw * 2 + j) * 16 + l16; if (m > 48) m = 48;
            const int oy = m / 7, ox = m % 7;
            base3[j] = c2L + (oy * 9 + ox) * 72 + quad * 8;
        }

        f32x4 acc3[2][4];
#pragma unroll
        for (int j = 0; j < 2; ++j)
#pragma unroll
            for (int ni = 0; ni < 4; ++ni)
                acc3[j][ni] = (f32x4){0.f, 0.f, 0.f, 0.f};

        bf16x8 aa[2][2];
#pragma unroll
        for (int j = 0; j < 2; ++j)
            aa[j][0] = *(const bf16x8*)(base3[j]);   // cc=0

#pragma unroll
        for (int cc = 0; cc < 18; ++cc) {
            const int cur = cc & 1, nxt = cur ^ 1;
            if (cc + 1 < 18) {
                const int cn = cc + 1;
                const int cpix = cn >> 1, ksn = cn & 1;
                const int aoff = ((cpix / 3) * 9 + (cpix % 3)) * 72 + ksn * 32;
#pragma unroll
                for (int ni = 0; ni < 4; ++ni)
                    w3[nxt][ni] = *(const bf16x8*)(Wpt3 + ((cn * 4 + ni) * 64 + lane) * 8);
#pragma unroll
                for (int j = 0; j < 2; ++j)
                    aa[j][nxt] = *(const bf16x8*)(base3[j] + aoff);
            }
#pragma unroll
            for (int j = 0; j < 2; ++j)
#pragma unroll
                for (int ni = 0; ni < 4; ++ni)
                    acc3[j][ni] = __builtin_amdgcn_mfma_f32_16x16x32_bf16(
                        aa[j][cur], w3[cur][ni], acc3[j][ni], 0, 0, 0);
        }

        u16* outp = c3f + ((long)t * 1024 + bl0 + wi) * 3136;
#pragma unroll
        for (int j = 0; j < 2; ++j)
#pragma unroll
            for (int ni = 0; ni < 4; ++ni)
#pragma unroll
                for (int rr = 0; rr < 4; ++rr) {
                    const int row = (lw * 2 + j) * 16 + quad * 4 + rr;
                    if (row < 49)
                        outp[row * 64 + ni * 16 + l16] =
                            f2b(fmaxf(acc3[j][ni][rr] + bv[ni], 0.f));
                }
    }
}

// ---------------------------------------------------------------------------
// Split-K MFMA GEMM, PARTIAL buffers.  128x128 tile, 4 waves, acc[4][4].
// 2-phase double-buffered global_load_lds staging (round-21 best).
// ---------------------------------------------------------------------------
__global__ __launch_bounds__(256) void gemm_skp(
    const u16* __restrict__ A, const u16* __restrict__ B0,
    const u16* __restrict__ B1,
    float* __restrict__ Cp, int M, int Mhalf, int N, int K, int Kc)
{
    __shared__ __attribute__((aligned(16))) u16 As[2][128 * 32];
    __shared__ __attribute__((aligned(16))) u16 Bs[2][128 * 32];

    const int tid  = threadIdx.x;
    const int wave = tid >> 6, lane = tid & 63;
    const int quad = lane >> 4, l16 = lane & 15;
    const int m0 = blockIdx.y * 128, n0 = blockIdx.x * 128;
    const u16* B = (m0 < Mhalf) ? B0 : B1;
    const int wm = (wave >> 1) * 64, wn = (wave & 1) * 64;
    const int kfrom = blockIdx.z * Kc;
    int kto = kfrom + Kc; if (kto > K) kto = K;
    float* C = Cp + (long)blockIdx.z * M * N;

    const int rl = lane >> 2, sg = lane & 3;     // 16 rows x 4 segs
    const u16* gA0 = A + (long)(m0 + wave * 32 + rl) * K + kfrom + sg * 8;
    const u16* gA1 = A + (long)(m0 + wave * 32 + 16 + rl) * K + kfrom + sg * 8;
    const u16* gB0 = B + (long)(n0 + wave * 32 + rl) * K + kfrom + sg * 8;
    const u16* gB1 = B + (long)(n0 + wave * 32 + 16 + rl) * K + kfrom + sg * 8;

    f32x4 acc[4][4];
#pragma unroll
    for (int mi = 0; mi < 4; ++mi)
#pragma unroll
        for (int ni = 0; ni < 4; ++ni)
            acc[mi][ni] = (f32x4){0.f, 0.f, 0.f, 0.f};

    const int nsteps = (kto - kfrom) >> 5;       // K-chunks are multiples of 32

    // prologue: stage step 0 into buffer 0
    {
        u16* lA = As[0] + wave * 1024;
        u16* lB = Bs[0] + wave * 1024;
        gl_lds16(gA0, lA);
        gl_lds16(gA1, lA + 512);
        gl_lds16(gB0, lB);
        gl_lds16(gB1, lB + 512);
    }
    __syncthreads();

    for (int s = 0; s < nsteps; ++s) {
        const int cur = s & 1, nxt = cur ^ 1;
        if (s + 1 < nsteps) {                    // issue next stage FIRST
            const int koff = (s + 1) * 32;
            u16* lA = As[nxt] + wave * 1024;
            u16* lB = Bs[nxt] + wave * 1024;
            gl_lds16(gA0 + koff, lA);
            gl_lds16(gA1 + koff, lA + 512);
            gl_lds16(gB0 + koff, lB);
            gl_lds16(gB1 + koff, lB + 512);
        }

        bf16x8 af[4], bfr[4];
#pragma unroll
        for (int mi = 0; mi < 4; ++mi)
            af[mi] = *(const bf16x8*)(As[cur] + (wm + mi * 16 + l16) * 32 + quad * 8);
#pragma unroll
        for (int ni = 0; ni < 4; ++ni)
            bfr[ni] = *(const bf16x8*)(Bs[cur] + (wn + ni * 16 + l16) * 32 + quad * 8);
#pragma unroll
        for (int mi = 0; mi < 4; ++mi)
#pragma unroll
            for (int ni = 0; ni < 4; ++ni)
                acc[mi][ni] = __builtin_amdgcn_mfma_f32_16x16x32_bf16(
                    af[mi], bfr[ni], acc[mi][ni], 0, 0, 0);

        __syncthreads();   // drains vmcnt (stage nxt complete) + protects cur
    }

#pragma unroll
    for (int mi = 0; mi < 4; ++mi)
#pragma unroll
        for (int ni = 0; ni < 4; ++ni) {
            int col = n0 + wn + ni * 16 + l16;
#pragma unroll
            for (int rr = 0; rr < 4; ++rr) {
                int row = m0 + wm + mi * 16 + quad * 4 + rr;
                C[(long)row * N + col] = acc[mi][ni][rr];
            }
        }
}

// ---------------------------------------------------------------------------
// ALL weight packs in one kernel.
// ---------------------------------------------------------------------------
__global__ __launch_bounds__(256) void pack_all(
    const float* __restrict__ vWl, const float* __restrict__ aWl,
    const float* __restrict__ vW1, const float* __restrict__ aW1,
    const float* __restrict__ vW2, const float* __restrict__ aW2,
    const float* __restrict__ vW3, const float* __restrict__ aW3,
    const float* __restrict__ avW, const float* __restrict__ aaW,
    const float* __restrict__ asW,
    const float* __restrict__ Wih, const float* __restrict__ Whh,
    u16* __restrict__ Wlb,
    u16* __restrict__ Wp1, u16* __restrict__ Wp2, u16* __restrict__ Wp3,
    u16* __restrict__ WTatt, u16* __restrict__ Bcat)
{
    __shared__ float row[3136];
    const int bid = blockIdx.x, tid = threadIdx.x;

    if (bid < 1024) {
        const int n = bid & 511;
        const float* src = (bid < 512) ? vWl : aWl;
        for (int i = tid; i < 3136; i += 256)
            row[i] = src[(long)n * 3136 + i];
        __syncthreads();
        u16* d = Wlb + (long)bid * 3136;
        for (int i = tid; i < 3136; i += 256) {
            int p = i >> 6, oc = i & 63;
            d[i] = f2b(row[oc * 49 + p]);
        }
        return;
    }

    const int idx = (bid - 1024) * 256 + tid;
    if (idx < 4096) {                // Wp1f: [t][ks*2+ni][lane][8], K=64, NF=2
        const float* s = (idx < 2048) ? vW1 : aW1;
        int j0 = idx & 2047;
        int jj = j0 & 7, lane = (j0 >> 3) & 63, rest = j0 >> 9;
        int ni = rest & 1, ks = rest >> 1;
        int oc = ni * 16 + (lane & 15);
        int k  = ks * 32 + (lane >> 4) * 8 + jj;
        Wp1[idx] = f2b(s[oc * 64 + k]);
    } else if (idx < 69632) {        // Wp2f: K=512, IC=32, KW=4, NF=4
        int i = idx - 4096;
        const float* s = (i < 32768) ? vW2 : aW2;
        int j0 = i & 32767;
        int jj = j0 & 7, lane = (j0 >> 3) & 63, rest = j0 >> 9;
        int ni = rest & 3, rest2 = rest >> 2;
        int ks = rest2 & 1, c = rest2 >> 1;
        int oc = ni * 16 + (lane & 15);
        int k  = c * 64 + ks * 32 + (lane >> 4) * 8 + jj;
        int pos = k >> 5, ic = k & 31;
        int ky = pos >> 2, kx = pos & 3;
        Wp2[i] = f2b(s[((oc * 32 + ic) * 4 + ky) * 4 + kx]);
    } else if (idx < 143360) {       // Wp3f: K=576, IC=64, KW=3, NF=4
        int i = idx - 69632;
        const float* s = (i < 36864) ? vW3 : aW3;
        int j0 = i % 36864;
        int jj = j0 & 7, lane = (j0 >> 3) & 63, rest = j0 >> 9;
        int ni = rest & 3, rest2 = rest >> 2;
        int ks = rest2 & 1, c = rest2 >> 1;
        int oc = ni * 16 + (lane & 15);
        int k  = c * 64 + ks * 32 + (lane >> 4) * 8 + jj;
        int pos = k >> 6, ic = k & 63;
        int ky = pos / 3, kx = pos % 3;
        Wp3[i] = f2b(s[((oc * 64 + ic) * 3 + ky) * 3 + kx]);
    } else if (idx < 180224) {       // WTatt: [1152][32]
        int i = idx - 143360;
        int k = i >> 5, j = i & 31;
        float v = (k < 512) ? avW[(long)j * 512 + k]
                : (k < 1024) ? aaW[(long)j * 512 + (k - 512)]
                : asW[(long)j * 128 + (k - 1024)];
        WTatt[i] = f2b(v);
    } else if (idx < 507904) {       // Bcat: [512][640]
        int i = idx - 180224;
        int n = i / 640, k = i % 640;
        Bcat[i] = f2b((k < 512) ? Wih[(long)n * 512 + k]
                                : Whh[(long)n * 128 + (k - 512)]);
    }
}

// ---------------------------------------------------------------------------
// FUSED: partial-sum reduce (8 slices) + bias + ReLU + LayerNorm (both
// towers, fused sum/sumsq shuffle reduction) + attention gating.
// ---------------------------------------------------------------------------
__global__ __launch_bounds__(256) void ln_attn(
    const float* __restrict__ ychp,       // [8][2048][512]
    const float* __restrict__ bl_v, const float* __restrict__ bl_a,
    const float* __restrict__ g_v,  const float* __restrict__ g_a,
    const float* __restrict__ be_v, const float* __restrict__ be_a,
    const float* __restrict__ h0,   const float* __restrict__ done,
    const u16* __restrict__ WT,
    const float* __restrict__ avb, const float* __restrict__ aab,
    const float* __restrict__ asb,
    const float* __restrict__ attW, const float* __restrict__ attb,
    float* __restrict__ vf_out, float* __restrict__ af_out,
    u16* __restrict__ Acat)
{
    __shared__ float vs[512], afs[512], hs[128], part[8][32], act[32], wsm[2];
    __shared__ float redS[4], redQ[4];
    const int b = blockIdx.x, tid = threadIdx.x;
    const int lane = tid & 63, wv = tid >> 6;

    if (tid < 128) hs[tid] = h0[b * 128 + tid];

#pragma unroll
    for (int tw = 0; tw < 2; ++tw) {
        const long row = tw ? (1024 + b) : b;
        const float* bias = tw ? bl_a : bl_v;
        const float* g    = tw ? g_a  : g_v;
        const float* be   = tw ? be_a : be_v;
        float* fo   = tw ? af_out : vf_out;
        float* dst  = tw ? afs : vs;

        float s0 = bias[tid], s1 = bias[tid + 256];
#pragma unroll
        for (int z = 0; z < 8; ++z) {
            const float* yr = ychp + (long)z * 1048576 + row * 512;
            s0 += yr[tid];
            s1 += yr[tid + 256];
        }
        float v0 = fmaxf(s0, 0.f), v1 = fmaxf(s1, 0.f);

        float sum = v0 + v1, sq = v0 * v0 + v1 * v1;
#pragma unroll
        for (int o = 32; o; o >>= 1) {
            sum += __shfl_xor(sum, o);
            sq  += __shfl_xor(sq, o);
        }
        if (lane == 0) { redS[wv] = sum; redQ[wv] = sq; }
        __syncthreads();
        const float ts = redS[0] + redS[1] + redS[2] + redS[3];
        const float tq = redQ[0] + redQ[1] + redQ[2] + redQ[3];
        const float mean = ts * (1.f / 512.f);
        const float var  = tq * (1.f / 512.f) - mean * mean;
        const float inv  = rsqrtf(var + 1e-5f);

        float o0 = (v0 - mean) * inv * g[tid]       + be[tid];
        float o1 = (v1 - mean) * inv * g[tid + 256] + be[tid + 256];
        dst[tid] = o0; dst[tid + 256] = o1;
        fo[(long)b * 512 + tid]       = o0;
        fo[(long)b * 512 + tid + 256] = o1;
        __syncthreads();
    }

    {
        const int j = tid & 31, g = tid >> 5;
        float a = 0.f;
#pragma unroll 8
        for (int k = g * 64; k < g * 64 + 64; ++k)
            a += vs[k] * b2f(WT[k * 32 + j]);
#pragma unroll 8
        for (int k = g * 64; k < g * 64 + 64; ++k)
            a += afs[k] * b2f(WT[(512 + k) * 32 + j]);
#pragma unroll 8
        for (int k = g * 16; k < g * 16 + 16; ++k)
            a += hs[k] * b2f(WT[(1024 + k) * 32 + j]);
        part[g][j] = a;
    }
    __syncthreads();
    if (tid < 32) {
        float a = avb[tid] + aab[tid] + asb[tid];
#pragma unroll
        for (int g2 = 0; g2 < 8; ++g2) a += part[g2][tid];
        act[tid] = tanhf(a);
    }
    __syncthreads();
    if (tid == 0) {
        float l0 = attb[0], l1 = attb[1];
        for (int j = 0; j < 32; ++j) {
            l0 += act[j] * attW[j];
            l1 += act[j] * attW[32 + j];
        }
        float mx = fmaxf(l0, l1);
        float e0 = expf(l0 - mx), e1 = expf(l1 - mx);
        float s = e0 + e1;
        wsm[0] = e0 / s; wsm[1] = e1 / s;
    }
    __syncthreads();
    const float w0 = wsm[0], w1 = wsm[1];
    const float m = 1.f - done[b];
    for (int i = tid; i < 512; i += 256)
        Acat[(long)b * 640 + i] = f2b(w0 * vs[i] + w1 * afs[i]);
    if (tid < 128)
        Acat[(long)b * 640 + 512 + tid] = f2b(m * hs[tid]);
}

// ---------------------------------------------------------------------------
// LSTM pointwise epilogue; sums the 10 gate partial slices inline.
// ---------------------------------------------------------------------------
__global__ __launch_bounds__(128) void lstm_fin(
    const float* __restrict__ gatesp,     // [10][1024][512]
    const float* __restrict__ bih, const float* __restrict__ bhh,
    const float* __restrict__ c0, const float* __restrict__ done,
    float* __restrict__ out)
{
    const int b = blockIdx.x, j = threadIdx.x;
    float gi = bih[j]       + bhh[j];
    float gf = bih[128 + j] + bhh[128 + j];
    float gg = bih[256 + j] + bhh[256 + j];
    float go = bih[384 + j] + bhh[384 + j];
#pragma unroll
    for (int z = 0; z < 10; ++z) {
        const float* G = gatesp + (long)z * 524288 + (long)b * 512;
        gi += G[j]; gf += G[128 + j]; gg += G[256 + j]; go += G[384 + j];
    }
    float m  = 1.f - done[b];
    float c  = m * c0[b * 128 + j];
    float si = 1.f / (1.f + expf(-gi));
    float sf = 1.f / (1.f + expf(-gf));
    float so = 1.f / (1.f + expf(-go));
    float cn = sf * c + si * tanhf(gg);
    float hn = so * tanhf(cn);
    out[b * 128 + j]          = hn;
    out[131072 + b * 128 + j] = cn;
}

// ---------------------------------------------------------------------------
extern "C" void kernel_launch(void* const* d_in, const int* in_sizes, int n_in,
                              void* d_out, int out_size, void* d_ws, size_t ws_size,
                              hipStream_t stream)
{
    (void)in_sizes; (void)n_in; (void)out_size; (void)ws_size;

    const float* x     = (const float*)d_in[0];
    const float* done  = (const float*)d_in[1];
    const float* h0    = (const float*)d_in[2];
    const float* c0in  = (const float*)d_in[3];
    const float* vW1   = (const float*)d_in[4];
    const float* vb1   = (const float*)d_in[5];
    const float* vW2   = (const float*)d_in[6];
    const float* vb2   = (const float*)d_in[7];
    const float* vW3   = (const float*)d_in[8];
    const float* vb3   = (const float*)d_in[9];
    const float* vWl   = (const float*)d_in[10];
    const float* vbl   = (const float*)d_in[11];
    const float* aW1   = (const float*)d_in[12];
    const float* ab1   = (const float*)d_in[13];
    const float* aW2   = (const float*)d_in[14];
    const float* ab2   = (const float*)d_in[15];
    const float* aW3   = (const float*)d_in[16];
    const float* ab3   = (const float*)d_in[17];
    const float* aWl   = (const float*)d_in[18];
    const float* abl   = (const float*)d_in[19];
    const float* vln_g = (const float*)d_in[20];
    const float* vln_b = (const float*)d_in[21];
    const float* aln_g = (const float*)d_in[22];
    const float* aln_b = (const float*)d_in[23];
    const float* att_vW = (const float*)d_in[24];
    const float* att_vb = (const float*)d_in[25];
    const float* att_aW = (const float*)d_in[26];
    const float* att_ab = (const float*)d_in[27];
    const float* att_sW = (const float*)d_in[28];
    const float* att_sb = (const float*)d_in[29];
    const float* attW  = (const float*)d_in[30];
    const float* attb  = (const float*)d_in[31];
    const float* Wih   = (const float*)d_in[32];
    const float* Whh   = (const float*)d_in[33];
    const float* bih   = (const float*)d_in[34];
    const float* bhh   = (const float*)d_in[35];

    float* out = (float*)d_out;
    float* vf_out = out + 262144;
    float* af_out = out + 786432;

    // ---- workspace carve ----
    char* p = (char*)d_ws;
    float* gatesp = (float*)p; p += 10ul * 1024 * 512 * 4;
    float* ychp   = (float*)p; p += 8ul * 2048 * 512 * 4;
    u16*   Acat   = (u16*)p;   p += 1024ul * 640 * 2;
    u16*   Bcat   = (u16*)p;   p += 512ul * 640 * 2;
    u16*   Wlb    = (u16*)p;   p += 2ul * 512 * 3136 * 2;
    u16*   Wp1    = (u16*)p;   p += 2ul * 2048 * 2;
    u16*   Wp2    = (u16*)p;   p += 2ul * 32768 * 2;
    u16*   Wp3    = (u16*)p;   p += 2ul * 36864 * 2;
    u16*   WTatt  = (u16*)p;   p += 36864ul * 2;
    u16*   c3f    = (u16*)p;

    // 1) all weight packs in one launch
    hipLaunchKernelGGL(pack_all, dim3(3008), dim3(256), 0, stream,
        vWl, aWl, vW1, aW1, vW2, aW2, vW3, aW3, att_vW, att_aW, att_sW,
        Wih, Whh, Wlb, Wp1, Wp2, Wp3, WTatt, Bcat);

    // 2) fused conv tower: one block per (2 images, tower), LDS-resident
    hipLaunchKernelGGL(tower_fused, dim3(512, 2), dim3(256), 0, stream,
        x, Wp1, Wp2, Wp3, vb1, ab1, vb2, ab2, vb3, ab3, c3f);

    // 3) tower linears: M=2048 GEMM, split-K 8 (Kc=416) -> 512 blocks = 2/CU
    hipLaunchKernelGGL(gemm_skp, dim3(4, 16, 8), dim3(256), 0, stream,
        c3f, Wlb, Wlb + 512ul * 3136, ychp, 2048, 1024, 512, 3136, 416);

    // 4) fused partial-reduce + LN (both towers) + attention -> vf/af + Acat
    hipLaunchKernelGGL(ln_attn, dim3(1024), dim3(256), 0, stream,
        ychp, vbl, abl, vln_g, aln_g, vln_b, aln_b, h0, done, WTatt,
        att_vb, att_ab, att_sb, attW, attb, vf_out, af_out, Acat);

    // 5) gates GEMM: split-K 10 (Kc=64) -> 320 blocks = 1.25/CU
    hipLaunchKernelGGL(gemm_skp, dim3(4, 8, 10), dim3(256), 0, stream,
        Acat, Bcat, Bcat, gatesp, 1024, 1 << 30, 512, 640, 64);

    // 6) LSTM epilogue (sums 10 partials)
    hipLaunchKernelGGL(lstm_fin, dim3(1024), dim3(128), 0, stream,
        gatesp, bih, bhh, c0in, done, out);
}

// Round 14
// 247.607 us; speedup vs baseline: 1.0395x; 1.0395x over previous
//
#include <hip/hip_runtime.h>

// ---------------------------------------------------------------------------
// AlignableCaslAgent forward.  Inputs f32, outputs f32.
// Round 24 = FINAL: revert to round-22 measured-best config (248.1us).
// Round-23's gates split-K 10 regressed (-9.3us: Kc=64 -> only 2 K-steps per
// block, pipeline degenerates + 24MB extra partial traffic) -> gates z=4 is
// the bracketed optimum.  All arcs closed by measurement:
//   tower: 2-img/block LDS-fused conv (round 20, ~54us)
//   gemm:  2-phase dbuf global_load_lds staging (round 21)
//   gemm1: split-K 8, Kc=416 -> 512 blocks = 2.0/CU (round 22)
//   gates: split-K 4, Kc=160 -> 128 blocks (z=10 measured worse)
//   ln_attn: shuffle-reduced LN + attention fusion, sums 8 slices
//   pack_all: single launch.
// Session: 297.5 -> 248.1us (-17%).
// ---------------------------------------------------------------------------

typedef unsigned short u16;
typedef unsigned int u32;
typedef __attribute__((ext_vector_type(8))) short bf16x8;
typedef __attribute__((ext_vector_type(4))) short bf16x4;
typedef __attribute__((ext_vector_type(4))) float f32x4;

__device__ __forceinline__ float b2f(u16 u) {
    union { u32 i; float f; } v; v.i = ((u32)u) << 16; return v.f;
}
__device__ __forceinline__ u16 f2b(float f) {
    union { float f; u32 i; } v; v.f = f;
    u32 r = v.i + 0x7fffu + ((v.i >> 16) & 1u);
    return (u16)(r >> 16);
}

// async global->LDS, 16B per lane; LDS dest = wave-uniform base + lane*16.
__device__ __forceinline__ void gl_lds16(const u16* g, u16* l) {
    __builtin_amdgcn_global_load_lds(
        (const __attribute__((address_space(1))) void*)g,
        (__attribute__((address_space(3))) void*)l,
        16, 0, 0);
}

// c1 LDS tile swizzle: XOR bits[6:4] with bits[9:7] (involution, keeps 16B
// alignment).  Valid per image region when region base % 1024 == 0.
__device__ __forceinline__ int swz(int byte) {
    return byte ^ (((byte >> 7) & 7) << 4);
}

// ---------------------------------------------------------------------------
// Fused conv tower, 2 images per block (round-20 version, arc closed).
// grid = (512, 2), 256 threads.  LDS 79424B -> 2 blocks/CU.
// ---------------------------------------------------------------------------
__global__ __launch_bounds__(256, 2) void tower_fused(
    const float* __restrict__ x,
    const u16* __restrict__ Wp1, const u16* __restrict__ Wp2,
    const u16* __restrict__ Wp3,
    const float* __restrict__ vb1, const float* __restrict__ ab1,
    const float* __restrict__ vb2, const float* __restrict__ ab2,
    const float* __restrict__ vb3, const float* __restrict__ ab3,
    u16* __restrict__ c3f)
{
    __shared__ __attribute__((aligned(16))) u16 scratch2[2 * 7056]; // img/c2L
    __shared__ __attribute__((aligned(16))) u16 c1L[2 * 400 * 32];  // swizzled

    const int tid = threadIdx.x;
    const int wave = tid >> 6, lane = tid & 63, quad = lane >> 4, l16 = lane & 15;
    const int bl0 = blockIdx.x * 2, t = blockIdx.y;
    const int wi = wave >> 1, lw = wave & 1;     // image index, local wave

    const u16* Wpt1 = Wp1 + t * 2048;
    const u16* Wpt2 = Wp2 + t * 32768;
    const u16* Wpt3 = Wp3 + t * 36864;

    // ---- conv1 weights first (in flight during image staging) ----
    bf16x8 bw[2][2];
#pragma unroll
    for (int ks = 0; ks < 2; ++ks)
#pragma unroll
        for (int ni = 0; ni < 2; ++ni)
            bw[ks][ni] = *(const bf16x8*)(Wpt1 + ((ks * 2 + ni) * 64 + lane) * 8);

    // ---- stage both images -> bf16 LDS ----
#pragma unroll
    for (int si = 0; si < 2; ++si) {
        const float* xim = x + ((long)(bl0 + si) * 2 + t) * 7056;
        u16* simg = scratch2 + si * 7056;
#pragma unroll
        for (int it = 0; it < 7; ++it) {
            const int e4 = (tid + it * 256) * 4;
            if (e4 < 7056) {
                float4 v = *(const float4*)(xim + e4);
                bf16x4 s;
                s[0] = (short)f2b(v.x); s[1] = (short)f2b(v.y);
                s[2] = (short)f2b(v.z); s[3] = (short)f2b(v.w);
                *(bf16x4*)(simg + e4) = s;
            }
        }
    }
    __syncthreads();

    const u16* simg = scratch2 + wi * 7056;      // this wave's image
    const int imgb = wi * 25600;                 // c1L image base (bytes)

    // ---- conv1: 400 outputs per image, K=64, OC=32; 12-13 tiles/wave ----
    {
        const float* b1 = t ? ab1 : vb1;
        const float bv0 = b1[l16], bv1 = b1[16 + l16];

        for (int tile = lw; tile < 25; tile += 2) {
            const int m = tile * 16 + l16;           // 0..399, always valid
            const int oy = m / 20, ox = m % 20;
            const u16* base = simg + (oy * 4) * 84 + ox * 4;
            const u16* ap0 = base + (quad) * 84;
            const u16* ap1 = base + (4 + quad) * 84;
            bf16x4 lo0 = *(const bf16x4*)(ap0);
            bf16x4 hi0 = *(const bf16x4*)(ap0 + 4);
            bf16x4 lo1 = *(const bf16x4*)(ap1);
            bf16x4 hi1 = *(const bf16x4*)(ap1 + 4);
            bf16x8 a0, a1;
#pragma unroll
            for (int j = 0; j < 4; ++j) {
                a0[j] = lo0[j]; a0[4 + j] = hi0[j];
                a1[j] = lo1[j]; a1[4 + j] = hi1[j];
            }
            f32x4 acc0 = (f32x4){0.f, 0.f, 0.f, 0.f};
            f32x4 acc1 = (f32x4){0.f, 0.f, 0.f, 0.f};
            acc0 = __builtin_amdgcn_mfma_f32_16x16x32_bf16(a0, bw[0][0], acc0, 0, 0, 0);
            acc1 = __builtin_amdgcn_mfma_f32_16x16x32_bf16(a0, bw[0][1], acc1, 0, 0, 0);
            acc0 = __builtin_amdgcn_mfma_f32_16x16x32_bf16(a1, bw[1][0], acc0, 0, 0, 0);
            acc1 = __builtin_amdgcn_mfma_f32_16x16x32_bf16(a1, bw[1][1], acc1, 0, 0, 0);
#pragma unroll
            for (int rr = 0; rr < 4; ++rr) {
                const int row = tile * 16 + quad * 4 + rr;
                *(u16*)((char*)c1L + imgb + swz((row * 32 + l16) * 2)) =
                    f2b(fmaxf(acc0[rr] + bv0, 0.f));
                *(u16*)((char*)c1L + imgb + swz((row * 32 + 16 + l16) * 2)) =
                    f2b(fmaxf(acc1[rr] + bv1, 0.f));
            }
        }
    }

    // ---- conv2 first weight set: issue BEFORE the barrier ----
    bf16x8 wb[2][4];
#pragma unroll
    for (int ni = 0; ni < 4; ++ni)
        wb[0][ni] = *(const bf16x8*)(Wpt2 + ((0 * 4 + ni) * 64 + lane) * 8);

    __syncthreads();

    // ---- conv2: 81 outputs per image, K=512, OC=64; 3 tiles/wave ----
    {
        const float* b2 = t ? ab2 : vb2;
        float bv[4];
#pragma unroll
        for (int ni = 0; ni < 4; ++ni) bv[ni] = b2[ni * 16 + l16];

        int bA[3];
#pragma unroll
        for (int j = 0; j < 3; ++j) {
            int m = (lw * 3 + j) * 16 + l16; if (m > 80) m = 80;
            const int oy = m / 9, ox = m % 9;
            bA[j] = ((oy * 2) * 20 + ox * 2) * 64 + quad * 16;   // bytes
        }

        f32x4 acc[3][4];
#pragma unroll
        for (int j = 0; j < 3; ++j)
#pragma unroll
            for (int ni = 0; ni < 4; ++ni)
                acc[j][ni] = (f32x4){0.f, 0.f, 0.f, 0.f};

        bf16x8 aA[3][2];
#pragma unroll
        for (int j = 0; j < 3; ++j)
            aA[j][0] = *(const bf16x8*)((const char*)c1L + imgb + swz(bA[j]));

#pragma unroll
        for (int pp = 0; pp < 16; ++pp) {    // window pixel = (ky,kx)
            const int cur = pp & 1, nxt = cur ^ 1;
            if (pp + 1 < 16) {
                const int pn = pp + 1;
                const int poffn = ((pn >> 2) * 20 + (pn & 3)) * 64;
#pragma unroll
                for (int ni = 0; ni < 4; ++ni)
                    wb[nxt][ni] = *(const bf16x8*)(Wpt2 + ((pn * 4 + ni) * 64 + lane) * 8);
#pragma unroll
                for (int j = 0; j < 3; ++j)
                    aA[j][nxt] = *(const bf16x8*)((const char*)c1L + imgb + swz(bA[j] + poffn));
            }
#pragma unroll
            for (int j = 0; j < 3; ++j)
#pragma unroll
                for (int ni = 0; ni < 4; ++ni)
                    acc[j][ni] = __builtin_amdgcn_mfma_f32_16x16x32_bf16(
                        aA[j][cur], wb[cur][ni], acc[j][ni], 0, 0, 0);
        }

        u16* c2L = scratch2 + wi * 5832;     // img data dead, alias [81][72]
#pragma unroll
        for (int j = 0; j < 3; ++j)
#pragma unroll
            for (int ni = 0; ni < 4; ++ni)
#pragma unroll
                for (int rr = 0; rr < 4; ++rr) {
                    const int r = (lw * 3 + j) * 16 + quad * 4 + rr;
                    if (r < 81)
                        c2L[r * 72 + ni * 16 + l16] =
                            f2b(fmaxf(acc[j][ni][rr] + bv[ni], 0.f));
                }
    }

    // ---- conv3 first weight set: issue BEFORE the barrier ----
    bf16x8 w3[2][4];
#pragma unroll
    for (int ni = 0; ni < 4; ++ni)
        w3[0][ni] = *(const bf16x8*)(Wpt3 + ((0 * 4 + ni) * 64 + lane) * 8);

    __syncthreads();

    // ---- conv3: 49 outputs per image, K=576, OC=64; 2 tiles/wave ----
    {
        const float* b3 = t ? ab3 : vb3;
        float bv[4];
#pragma unroll
        for (int ni = 0; ni < 4; ++ni) bv[ni] = b3[ni * 16 + l16];

        const u16* c2L = scratch2 + wi * 5832;
        const u16* base3[2];
#pragma unroll
        for (int j = 0; j < 2; ++j) {
            int m = (lw * 2 + j) * 16 + l16; if (m > 48) m = 48;
            const int oy = m / 7, ox = m % 7;
            base3[j] = c2L + (oy * 9 + ox) * 72 + quad * 8;
        }

        f32x4 acc3[2][4];
#pragma unroll
        for (int j = 0; j < 2; ++j)
#pragma unroll
            for (int ni = 0; ni < 4; ++ni)
                acc3[j][ni] = (f32x4){0.f, 0.f, 0.f, 0.f};

        bf16x8 aa[2][2];
#pragma unroll
        for (int j = 0; j < 2; ++j)
            aa[j][0] = *(const bf16x8*)(base3[j]);   // cc=0

#pragma unroll
        for (int cc = 0; cc < 18; ++cc) {
            const int cur = cc & 1, nxt = cur ^ 1;
            if (cc + 1 < 18) {
                const int cn = cc + 1;
                const int cpix = cn >> 1, ksn = cn & 1;
                const int aoff = ((cpix / 3) * 9 + (cpix % 3)) * 72 + ksn * 32;
#pragma unroll
                for (int ni = 0; ni < 4; ++ni)
                    w3[nxt][ni] = *(const bf16x8*)(Wpt3 + ((cn * 4 + ni) * 64 + lane) * 8);
#pragma unroll
                for (int j = 0; j < 2; ++j)
                    aa[j][nxt] = *(const bf16x8*)(base3[j] + aoff);
            }
#pragma unroll
            for (int j = 0; j < 2; ++j)
#pragma unroll
                for (int ni = 0; ni < 4; ++ni)
                    acc3[j][ni] = __builtin_amdgcn_mfma_f32_16x16x32_bf16(
                        aa[j][cur], w3[cur][ni], acc3[j][ni], 0, 0, 0);
        }

        u16* outp = c3f + ((long)t * 1024 + bl0 + wi) * 3136;
#pragma unroll
        for (int j = 0; j < 2; ++j)
#pragma unroll
            for (int ni = 0; ni < 4; ++ni)
#pragma unroll
                for (int rr = 0; rr < 4; ++rr) {
                    const int row = (lw * 2 + j) * 16 + quad * 4 + rr;
                    if (row < 49)
                        outp[row * 64 + ni * 16 + l16] =
                            f2b(fmaxf(acc3[j][ni][rr] + bv[ni], 0.f));
                }
    }
}

// ---------------------------------------------------------------------------
// Split-K MFMA GEMM, PARTIAL buffers.  128x128 tile, 4 waves, acc[4][4].
// 2-phase double-buffered global_load_lds staging (round-21 best).
// ---------------------------------------------------------------------------
__global__ __launch_bounds__(256) void gemm_skp(
    const u16* __restrict__ A, const u16* __restrict__ B0,
    const u16* __restrict__ B1,
    float* __restrict__ Cp, int M, int Mhalf, int N, int K, int Kc)
{
    __shared__ __attribute__((aligned(16))) u16 As[2][128 * 32];
    __shared__ __attribute__((aligned(16))) u16 Bs[2][128 * 32];

    const int tid  = threadIdx.x;
    const int wave = tid >> 6, lane = tid & 63;
    const int quad = lane >> 4, l16 = lane & 15;
    const int m0 = blockIdx.y * 128, n0 = blockIdx.x * 128;
    const u16* B = (m0 < Mhalf) ? B0 : B1;
    const int wm = (wave >> 1) * 64, wn = (wave & 1) * 64;
    const int kfrom = blockIdx.z * Kc;
    int kto = kfrom + Kc; if (kto > K) kto = K;
    float* C = Cp + (long)blockIdx.z * M * N;

    const int rl = lane >> 2, sg = lane & 3;     // 16 rows x 4 segs
    const u16* gA0 = A + (long)(m0 + wave * 32 + rl) * K + kfrom + sg * 8;
    const u16* gA1 = A + (long)(m0 + wave * 32 + 16 + rl) * K + kfrom + sg * 8;
    const u16* gB0 = B + (long)(n0 + wave * 32 + rl) * K + kfrom + sg * 8;
    const u16* gB1 = B + (long)(n0 + wave * 32 + 16 + rl) * K + kfrom + sg * 8;

    f32x4 acc[4][4];
#pragma unroll
    for (int mi = 0; mi < 4; ++mi)
#pragma unroll
        for (int ni = 0; ni < 4; ++ni)
            acc[mi][ni] = (f32x4){0.f, 0.f, 0.f, 0.f};

    const int nsteps = (kto - kfrom) >> 5;       // K-chunks are multiples of 32

    // prologue: stage step 0 into buffer 0
    {
        u16* lA = As[0] + wave * 1024;
        u16* lB = Bs[0] + wave * 1024;
        gl_lds16(gA0, lA);
        gl_lds16(gA1, lA + 512);
        gl_lds16(gB0, lB);
        gl_lds16(gB1, lB + 512);
    }
    __syncthreads();

    for (int s = 0; s < nsteps; ++s) {
        const int cur = s & 1, nxt = cur ^ 1;
        if (s + 1 < nsteps) {                    // issue next stage FIRST
            const int koff = (s + 1) * 32;
            u16* lA = As[nxt] + wave * 1024;
            u16* lB = Bs[nxt] + wave * 1024;
            gl_lds16(gA0 + koff, lA);
            gl_lds16(gA1 + koff, lA + 512);
            gl_lds16(gB0 + koff, lB);
            gl_lds16(gB1 + koff, lB + 512);
        }

        bf16x8 af[4], bfr[4];
#pragma unroll
        for (int mi = 0; mi < 4; ++mi)
            af[mi] = *(const bf16x8*)(As[cur] + (wm + mi * 16 + l16) * 32 + quad * 8);
#pragma unroll
        for (int ni = 0; ni < 4; ++ni)
            bfr[ni] = *(const bf16x8*)(Bs[cur] + (wn + ni * 16 + l16) * 32 + quad * 8);
#pragma unroll
        for (int mi = 0; mi < 4; ++mi)
#pragma unroll
            for (int ni = 0; ni < 4; ++ni)
                acc[mi][ni] = __builtin_amdgcn_mfma_f32_16x16x32_bf16(
                    af[mi], bfr[ni], acc[mi][ni], 0, 0, 0);

        __syncthreads();   // drains vmcnt (stage nxt complete) + protects cur
    }

#pragma unroll
    for (int mi = 0; mi < 4; ++mi)
#pragma unroll
        for (int ni = 0; ni < 4; ++ni) {
            int col = n0 + wn + ni * 16 + l16;
#pragma unroll
            for (int rr = 0; rr < 4; ++rr) {
                int row = m0 + wm + mi * 16 + quad * 4 + rr;
                C[(long)row * N + col] = acc[mi][ni][rr];
            }
        }
}

// ---------------------------------------------------------------------------
// ALL weight packs in one kernel.
// ---------------------------------------------------------------------------
__global__ __launch_bounds__(256) void pack_all(
    const float* __restrict__ vWl, const float* __restrict__ aWl,
    const float* __restrict__ vW1, const float* __restrict__ aW1,
    const float* __restrict__ vW2, const float* __restrict__ aW2,
    const float* __restrict__ vW3, const float* __restrict__ aW3,
    const float* __restrict__ avW, const float* __restrict__ aaW,
    const float* __restrict__ asW,
    const float* __restrict__ Wih, const float* __restrict__ Whh,
    u16* __restrict__ Wlb,
    u16* __restrict__ Wp1, u16* __restrict__ Wp2, u16* __restrict__ Wp3,
    u16* __restrict__ WTatt, u16* __restrict__ Bcat)
{
    __shared__ float row[3136];
    const int bid = blockIdx.x, tid = threadIdx.x;

    if (bid < 1024) {
        const int n = bid & 511;
        const float* src = (bid < 512) ? vWl : aWl;
        for (int i = tid; i < 3136; i += 256)
            row[i] = src[(long)n * 3136 + i];
        __syncthreads();
        u16* d = Wlb + (long)bid * 3136;
        for (int i = tid; i < 3136; i += 256) {
            int p = i >> 6, oc = i & 63;
            d[i] = f2b(row[oc * 49 + p]);
        }
        return;
    }

    const int idx = (bid - 1024) * 256 + tid;
    if (idx < 4096) {                // Wp1f: [t][ks*2+ni][lane][8], K=64, NF=2
        const float* s = (idx < 2048) ? vW1 : aW1;
        int j0 = idx & 2047;
        int jj = j0 & 7, lane = (j0 >> 3) & 63, rest = j0 >> 9;
        int ni = rest & 1, ks = rest >> 1;
        int oc = ni * 16 + (lane & 15);
        int k  = ks * 32 + (lane >> 4) * 8 + jj;
        Wp1[idx] = f2b(s[oc * 64 + k]);
    } else if (idx < 69632) {        // Wp2f: K=512, IC=32, KW=4, NF=4
        int i = idx - 4096;
        const float* s = (i < 32768) ? vW2 : aW2;
        int j0 = i & 32767;
        int jj = j0 & 7, lane = (j0 >> 3) & 63, rest = j0 >> 9;
        int ni = rest & 3, rest2 = rest >> 2;
        int ks = rest2 & 1, c = rest2 >> 1;
        int oc = ni * 16 + (lane & 15);
        int k  = c * 64 + ks * 32 + (lane >> 4) * 8 + jj;
        int pos = k >> 5, ic = k & 31;
        int ky = pos >> 2, kx = pos & 3;
        Wp2[i] = f2b(s[((oc * 32 + ic) * 4 + ky) * 4 + kx]);
    } else if (idx < 143360) {       // Wp3f: K=576, IC=64, KW=3, NF=4
        int i = idx - 69632;
        const float* s = (i < 36864) ? vW3 : aW3;
        int j0 = i % 36864;
        int jj = j0 & 7, lane = (j0 >> 3) & 63, rest = j0 >> 9;
        int ni = rest & 3, rest2 = rest >> 2;
        int ks = rest2 & 1, c = rest2 >> 1;
        int oc = ni * 16 + (lane & 15);
        int k  = c * 64 + ks * 32 + (lane >> 4) * 8 + jj;
        int pos = k >> 6, ic = k & 63;
        int ky = pos / 3, kx = pos % 3;
        Wp3[i] = f2b(s[((oc * 64 + ic) * 3 + ky) * 3 + kx]);
    } else if (idx < 180224) {       // WTatt: [1152][32]
        int i = idx - 143360;
        int k = i >> 5, j = i & 31;
        float v = (k < 512) ? avW[(long)j * 512 + k]
                : (k < 1024) ? aaW[(long)j * 512 + (k - 512)]
                : asW[(long)j * 128 + (k - 1024)];
        WTatt[i] = f2b(v);
    } else if (idx < 507904) {       // Bcat: [512][640]
        int i = idx - 180224;
        int n = i / 640, k = i % 640;
        Bcat[i] = f2b((k < 512) ? Wih[(long)n * 512 + k]
                                : Whh[(long)n * 128 + (k - 512)]);
    }
}

// ---------------------------------------------------------------------------
// FUSED: partial-sum reduce (8 slices) + bias + ReLU + LayerNorm (both
// towers, fused sum/sumsq shuffle reduction) + attention gating.
// ---------------------------------------------------------------------------
__global__ __launch_bounds__(256) void ln_attn(
    const float* __restrict__ ychp,       // [8][2048][512]
    const float* __restrict__ bl_v, const float* __restrict__ bl_a,
    const float* __restrict__ g_v,  const float* __restrict__ g_a,
    const float* __restrict__ be_v, const float* __restrict__ be_a,
    const float* __restrict__ h0,   const float* __restrict__ done,
    const u16* __restrict__ WT,
    const float* __restrict__ avb, const float* __restrict__ aab,
    const float* __restrict__ asb,
    const float* __restrict__ attW, const float* __restrict__ attb,
    float* __restrict__ vf_out, float* __restrict__ af_out,
    u16* __restrict__ Acat)
{
    __shared__ float vs[512], afs[512], hs[128], part[8][32], act[32], wsm[2];
    __shared__ float redS[4], redQ[4];
    const int b = blockIdx.x, tid = threadIdx.x;
    const int lane = tid & 63, wv = tid >> 6;

    if (tid < 128) hs[tid] = h0[b * 128 + tid];

#pragma unroll
    for (int tw = 0; tw < 2; ++tw) {
        const long row = tw ? (1024 + b) : b;
        const float* bias = tw ? bl_a : bl_v;
        const float* g    = tw ? g_a  : g_v;
        const float* be   = tw ? be_a : be_v;
        float* fo   = tw ? af_out : vf_out;
        float* dst  = tw ? afs : vs;

        float s0 = bias[tid], s1 = bias[tid + 256];
#pragma unroll
        for (int z = 0; z < 8; ++z) {
            const float* yr = ychp + (long)z * 1048576 + row * 512;
            s0 += yr[tid];
            s1 += yr[tid + 256];
        }
        float v0 = fmaxf(s0, 0.f), v1 = fmaxf(s1, 0.f);

        float sum = v0 + v1, sq = v0 * v0 + v1 * v1;
#pragma unroll
        for (int o = 32; o; o >>= 1) {
            sum += __shfl_xor(sum, o);
            sq  += __shfl_xor(sq, o);
        }
        if (lane == 0) { redS[wv] = sum; redQ[wv] = sq; }
        __syncthreads();
        const float ts = redS[0] + redS[1] + redS[2] + redS[3];
        const float tq = redQ[0] + redQ[1] + redQ[2] + redQ[3];
        const float mean = ts * (1.f / 512.f);
        const float var  = tq * (1.f / 512.f) - mean * mean;
        const float inv  = rsqrtf(var + 1e-5f);

        float o0 = (v0 - mean) * inv * g[tid]       + be[tid];
        float o1 = (v1 - mean) * inv * g[tid + 256] + be[tid + 256];
        dst[tid] = o0; dst[tid + 256] = o1;
        fo[(long)b * 512 + tid]       = o0;
        fo[(long)b * 512 + tid + 256] = o1;
        __syncthreads();
    }

    {
        const int j = tid & 31, g = tid >> 5;
        float a = 0.f;
#pragma unroll 8
        for (int k = g * 64; k < g * 64 + 64; ++k)
            a += vs[k] * b2f(WT[k * 32 + j]);
#pragma unroll 8
        for (int k = g * 64; k < g * 64 + 64; ++k)
            a += afs[k] * b2f(WT[(512 + k) * 32 + j]);
#pragma unroll 8
        for (int k = g * 16; k < g * 16 + 16; ++k)
            a += hs[k] * b2f(WT[(1024 + k) * 32 + j]);
        part[g][j] = a;
    }
    __syncthreads();
    if (tid < 32) {
        float a = avb[tid] + aab[tid] + asb[tid];
#pragma unroll
        for (int g2 = 0; g2 < 8; ++g2) a += part[g2][tid];
        act[tid] = tanhf(a);
    }
    __syncthreads();
    if (tid == 0) {
        float l0 = attb[0], l1 = attb[1];
        for (int j = 0; j < 32; ++j) {
            l0 += act[j] * attW[j];
            l1 += act[j] * attW[32 + j];
        }
        float mx = fmaxf(l0, l1);
        float e0 = expf(l0 - mx), e1 = expf(l1 - mx);
        float s = e0 + e1;
        wsm[0] = e0 / s; wsm[1] = e1 / s;
    }
    __syncthreads();
    const float w0 = wsm[0], w1 = wsm[1];
    const float m = 1.f - done[b];
    for (int i = tid; i < 512; i += 256)
        Acat[(long)b * 640 + i] = f2b(w0 * vs[i] + w1 * afs[i]);
    if (tid < 128)
        Acat[(long)b * 640 + 512 + tid] = f2b(m * hs[tid]);
}

// ---------------------------------------------------------------------------
// LSTM pointwise epilogue; sums the 4 gate partial slices inline.
// ---------------------------------------------------------------------------
__global__ __launch_bounds__(128) void lstm_fin(
    const float* __restrict__ gatesp,     // [4][1024][512]
    const float* __restrict__ bih, const float* __restrict__ bhh,
    const float* __restrict__ c0, const float* __restrict__ done,
    float* __restrict__ out)
{
    const int b = blockIdx.x, j = threadIdx.x;
    float gi = bih[j]       + bhh[j];
    float gf = bih[128 + j] + bhh[128 + j];
    float gg = bih[256 + j] + bhh[256 + j];
    float go = bih[384 + j] + bhh[384 + j];
#pragma unroll
    for (int z = 0; z < 4; ++z) {
        const float* G = gatesp + (long)z * 524288 + (long)b * 512;
        gi += G[j]; gf += G[128 + j]; gg += G[256 + j]; go += G[384 + j];
    }
    float m  = 1.f - done[b];
    float c  = m * c0[b * 128 + j];
    float si = 1.f / (1.f + expf(-gi));
    float sf = 1.f / (1.f + expf(-gf));
    float so = 1.f / (1.f + expf(-go));
    float cn = sf * c + si * tanhf(gg);
    float hn = so * tanhf(cn);
    out[b * 128 + j]          = hn;
    out[131072 + b * 128 + j] = cn;
}

// ---------------------------------------------------------------------------
extern "C" void kernel_launch(void* const* d_in, const int* in_sizes, int n_in,
                              void* d_out, int out_size, void* d_ws, size_t ws_size,
                              hipStream_t stream)
{
    (void)in_sizes; (void)n_in; (void)out_size; (void)ws_size;

    const float* x     = (const float*)d_in[0];
    const float* done  = (const float*)d_in[1];
    const float* h0    = (const float*)d_in[2];
    const float* c0in  = (const float*)d_in[3];
    const float* vW1   = (const float*)d_in[4];
    const float* vb1   = (const float*)d_in[5];
    const float* vW2   = (const float*)d_in[6];
    const float* vb2   = (const float*)d_in[7];
    const float* vW3   = (const float*)d_in[8];
    const float* vb3   = (const float*)d_in[9];
    const float* vWl   = (const float*)d_in[10];
    const float* vbl   = (const float*)d_in[11];
    const float* aW1   = (const float*)d_in[12];
    const float* ab1   = (const float*)d_in[13];
    const float* aW2   = (const float*)d_in[14];
    const float* ab2   = (const float*)d_in[15];
    const float* aW3   = (const float*)d_in[16];
    const float* ab3   = (const float*)d_in[17];
    const float* aWl   = (const float*)d_in[18];
    const float* abl   = (const float*)d_in[19];
    const float* vln_g = (const float*)d_in[20];
    const float* vln_b = (const float*)d_in[21];
    const float* aln_g = (const float*)d_in[22];
    const float* aln_b = (const float*)d_in[23];
    const float* att_vW = (const float*)d_in[24];
    const float* att_vb = (const float*)d_in[25];
    const float* att_aW = (const float*)d_in[26];
    const float* att_ab = (const float*)d_in[27];
    const float* att_sW = (const float*)d_in[28];
    const float* att_sb = (const float*)d_in[29];
    const float* attW  = (const float*)d_in[30];
    const float* attb  = (const float*)d_in[31];
    const float* Wih   = (const float*)d_in[32];
    const float* Whh   = (const float*)d_in[33];
    const float* bih   = (const float*)d_in[34];
    const float* bhh   = (const float*)d_in[35];

    float* out = (float*)d_out;
    float* vf_out = out + 262144;
    float* af_out = out + 786432;

    // ---- workspace carve ----
    char* p = (char*)d_ws;
    float* gatesp = (float*)p; p += 4ul * 1024 * 512 * 4;
    float* ychp   = (float*)p; p += 8ul * 2048 * 512 * 4;
    u16*   Acat   = (u16*)p;   p += 1024ul * 640 * 2;
    u16*   Bcat   = (u16*)p;   p += 512ul * 640 * 2;
    u16*   Wlb    = (u16*)p;   p += 2ul * 512 * 3136 * 2;
    u16*   Wp1    = (u16*)p;   p += 2ul * 2048 * 2;
    u16*   Wp2    = (u16*)p;   p += 2ul * 32768 * 2;
    u16*   Wp3    = (u16*)p;   p += 2ul * 36864 * 2;
    u16*   WTatt  = (u16*)p;   p += 36864ul * 2;
    u16*   c3f    = (u16*)p;

    // 1) all weight packs in one launch
    hipLaunchKernelGGL(pack_all, dim3(3008), dim3(256), 0, stream,
        vWl, aWl, vW1, aW1, vW2, aW2, vW3, aW3, att_vW, att_aW, att_sW,
        Wih, Whh, Wlb, Wp1, Wp2, Wp3, WTatt, Bcat);

    // 2) fused conv tower: one block per (2 images, tower), LDS-resident
    hipLaunchKernelGGL(tower_fused, dim3(512, 2), dim3(256), 0, stream,
        x, Wp1, Wp2, Wp3, vb1, ab1, vb2, ab2, vb3, ab3, c3f);

    // 3) tower linears: M=2048 GEMM, split-K 8 (Kc=416) -> 512 blocks = 2/CU
    hipLaunchKernelGGL(gemm_skp, dim3(4, 16, 8), dim3(256), 0, stream,
        c3f, Wlb, Wlb + 512ul * 3136, ychp, 2048, 1024, 512, 3136, 416);

    // 4) fused partial-reduce + LN (both towers) + attention -> vf/af + Acat
    hipLaunchKernelGGL(ln_attn, dim3(1024), dim3(256), 0, stream,
        ychp, vbl, abl, vln_g, aln_g, vln_b, aln_b, h0, done, WTatt,
        att_vb, att_ab, att_sb, attW, attb, vf_out, af_out, Acat);

    // 5) gates GEMM: split-K 4 (Kc=160) - bracketed optimum (z=10 was worse)
    hipLaunchKernelGGL(gemm_skp, dim3(4, 8, 4), dim3(256), 0, stream,
        Acat, Bcat, Bcat, gatesp, 1024, 1 << 30, 512, 640, 160);

    // 6) LSTM epilogue (sums 4 partials)
    hipLaunchKernelGGL(lstm_fin, dim3(1024), dim3(128), 0, stream,
        gatesp, bih, bhh, c0in, done, out);
}